// Round 8
// baseline (231.555 us; speedup 1.0000x reference)
//
#include <hip/hip_runtime.h>

#define N_NODES 100000
#define N_EDGES 600000
#define DIM 128
#define NUM_RELS 8
#define NBINS (NUM_RELS * N_NODES)          // node-major: key = dst*8 + r
#define SCAN_NB ((NBINS + 1023) / 1024)     // 782
#define XBLOCKS 6250
#define TBLOCKS 576
#define HBLOCKS ((N_EDGES + 255) / 256)

typedef unsigned int u32;
typedef __attribute__((ext_vector_type(8))) short bf16x8;
typedef __attribute__((ext_vector_type(4))) float f32x4;

__device__ __forceinline__ u32 pack2_bf16_rn(float lo, float hi) {
    u32 a = __float_as_uint(lo);
    u32 b = __float_as_uint(hi);
    a += 0x7fffu + ((a >> 16) & 1u);
    b += 0x7fffu + ((b >> 16) & 1u);
    return (a >> 16) | (b & 0xffff0000u);
}

// ---------------------------------------------------------------------------
// prep = convert_x | transpose_w | hist+rank
__global__ __launch_bounds__(256) void prep(
    const float* __restrict__ x, uint4* __restrict__ x_bf,
    const float* __restrict__ W, const float* __restrict__ W_root,
    unsigned short* __restrict__ Wt,
    const int* __restrict__ ei, const int* __restrict__ et,
    u32* __restrict__ hist, u32* __restrict__ rank) {
    int b = blockIdx.x, tid = threadIdx.x;
    if (b < XBLOCKS) {
        int t = b * 256 + tid;
        const float4* p = reinterpret_cast<const float4*>(x) + (size_t)t * 2;
        float4 v0 = p[0], v1 = p[1];
        uint4 o;
        o.x = pack2_bf16_rn(v0.x, v0.y);
        o.y = pack2_bf16_rn(v0.z, v0.w);
        o.z = pack2_bf16_rn(v1.x, v1.y);
        o.w = pack2_bf16_rn(v1.z, v1.w);
        x_bf[t] = o;
    } else if (b < XBLOCKS + TBLOCKS) {
        int t = (b - XBLOCKS) * 256 + tid;
        int c  = t >> 14;
        int kn = t & 16383;
        int k = kn >> 7, n = kn & 127;
        float v = (c == 0) ? W_root[kn] : W[(size_t)(c - 1) * DIM * DIM + kn];
        u32 bb = __float_as_uint(v);
        bb += 0x7fffu + ((bb >> 16) & 1u);
        Wt[(size_t)c * 16384 + n * 128 + k] = (unsigned short)(bb >> 16);
    } else {
        int e = (b - XBLOCKS - TBLOCKS) * 256 + tid;
        if (e < N_EDGES) {
            int dst = ei[N_EDGES + e];
            int r   = et[e];
            rank[e] = atomicAdd(&hist[(size_t)dst * NUM_RELS + r], 1u);
        }
    }
}

// ---------------------------------------------------------------------------
__global__ __launch_bounds__(256) void scan1(const u32* __restrict__ hist,
                                             u32* __restrict__ bsum) {
    __shared__ u32 sh[256];
    int t = threadIdx.x;
    size_t base = (size_t)blockIdx.x * 1024 + t * 4;
    u32 s = 0;
#pragma unroll
    for (int j = 0; j < 4; ++j) { size_t i = base + j; if (i < NBINS) s += hist[i]; }
    sh[t] = s; __syncthreads();
    for (int off = 128; off > 0; off >>= 1) {
        if (t < off) sh[t] += sh[t + off];
        __syncthreads();
    }
    if (t == 0) bsum[blockIdx.x] = sh[0];
}

__global__ __launch_bounds__(256) void scan2(u32* __restrict__ bsum, int nb) {
    __shared__ u32 sh[256];
    int t = threadIdx.x;
    u32 v[4]; u32 s = 0;
#pragma unroll
    for (int j = 0; j < 4; ++j) { int i = t * 4 + j; v[j] = (i < nb) ? bsum[i] : 0; s += v[j]; }
    sh[t] = s; __syncthreads();
    for (int off = 1; off < 256; off <<= 1) {
        u32 add = (t >= off) ? sh[t - off] : 0;
        __syncthreads();
        sh[t] += add;
        __syncthreads();
    }
    u32 run = (t > 0) ? sh[t - 1] : 0;
#pragma unroll
    for (int j = 0; j < 4; ++j) { int i = t * 4 + j; if (i < nb) bsum[i] = run; run += v[j]; }
}

__global__ __launch_bounds__(256) void scan3(const u32* __restrict__ hist,
                                             const u32* __restrict__ bsum,
                                             u32* __restrict__ starts) {
    __shared__ u32 sh[256];
    int t = threadIdx.x;
    size_t base = (size_t)blockIdx.x * 1024 + t * 4;
    u32 v[4]; u32 s = 0;
#pragma unroll
    for (int j = 0; j < 4; ++j) { size_t i = base + j; v[j] = (i < NBINS) ? hist[i] : 0; s += v[j]; }
    sh[t] = s; __syncthreads();
    for (int off = 1; off < 256; off <<= 1) {
        u32 add = (t >= off) ? sh[t - off] : 0;
        __syncthreads();
        sh[t] += add;
        __syncthreads();
    }
    u32 run = bsum[blockIdx.x] + ((t > 0) ? sh[t - 1] : 0);
#pragma unroll
    for (int j = 0; j < 4; ++j) {
        size_t i = base + j;
        if (i < NBINS) {
            starts[i] = run;
            if (i == NBINS - 1) starts[NBINS] = run + v[j];
            run += v[j];
        }
    }
}

// pos = starts[key] + rank[e]; spk = src | local_bin<<17, local_bin=(dst&31)*8+r
__global__ __launch_bounds__(256) void reorder(const int* __restrict__ ei,
                                               const int* __restrict__ et,
                                               const u32* __restrict__ starts,
                                               const u32* __restrict__ rank,
                                               u32* __restrict__ spk) {
    int e = blockIdx.x * 256 + threadIdx.x;
    if (e >= N_EDGES) return;
    int dst = ei[N_EDGES + e];
    int r   = et[e];
    u32 bin = (u32)((dst & 31) * NUM_RELS + r);
    spk[starts[(size_t)dst * NUM_RELS + r] + rank[e]] = (u32)ei[e] | (bin << 17);
}

// ---------------------------------------------------------------------------
// write mean row (bf16, uint2 per lane of the owning half-wave) for finished bin
#define FLUSHH() do { \
    float sc_ = __builtin_amdgcn_rcpf((float)rcnt); \
    uint2 pv_; \
    pv_.x = pack2_bf16_rn(a0 * sc_, a1 * sc_); \
    pv_.y = pack2_bf16_rn(a2 * sc_, a3 * sc_); \
    u32 sw_ = ((u32)cur_bin >> 3) & 15u; \
    *reinterpret_cast<uint2*>(&ACC[(u32)cur_bin * 64u + \
        (((((u32)l32 >> 1) ^ sw_) << 2) | (((u32)l32 & 1u) << 1))]) = pv_; \
} while (0)

// Fused RGCN: half-wave register aggregation into 64KB LDS + 9-chunk MFMA.
// Block = 32 dsts (grid 3125), 512 thr = 8 waves = 16 half-wave units (2 dsts each).
// Each gather inst fetches TWO 256B rows (uint2/lane) -> 2x rows in flight vs R7.
__global__ __launch_bounds__(512, 4) void rgcn_fused(
    const uint2* __restrict__ x2,     // x_bf rows of 32 uint2
    const uint4* __restrict__ x16,    // x_bf rows of 16 uint4
    const uint4* __restrict__ Wt,     // 9 * 2048 uint4
    const u32*  __restrict__ starts,  // [NBINS+1]
    const u32*  __restrict__ spk,     // [E] sorted: src | local_bin<<17
    const float* __restrict__ bias,
    float* __restrict__ out) {
    extern __shared__ u32 ACC[];      // [256 bins][64 u32] bf16 means, 64 KB
    const int tid = threadIdx.x, w = tid >> 6, lane = tid & 63;
    const int g = lane >> 4, m = lane & 15;
    const int h = lane >> 5, l32 = lane & 31;
    const int unit = w * 2 + h;                     // 0..15, owns local bins [unit*16,+16)
    const int rowbase = blockIdx.x * 32;

    // zero ACC
    uint4* az = reinterpret_cast<uint4*>(ACC);
#pragma unroll
    for (int i = 0; i < 8; ++i) az[tid + i * 512] = make_uint4(0u, 0u, 0u, 0u);
    __syncthreads();

    // ---- phase 1: per-half-wave aggregation over sorted runs
    {
        const u32 elo = starts[(size_t)blockIdx.x * 256 + unit * 16];
        const u32 ehi = starts[(size_t)blockIdx.x * 256 + unit * 16 + 16];
        int cur_bin = -1, rcnt = 0;
        float a0 = 0.f, a1 = 0.f, a2 = 0.f, a3 = 0.f;

        for (u32 base = elo; base < ehi; base += 32) {
            const int bn = min(32, (int)(ehi - base));       // per-half
            u32 pk_l = 0;
            if (l32 < bn) pk_l = spk[base + l32];            // stage 32 edges/half
            for (int j0 = 0; j0 < bn; j0 += 8) {
                const int lim = bn - j0;
                uint2 v[8];
#pragma unroll
                for (int q = 0; q < 8; ++q) {                // 8 rows/half in flight
                    int idx = j0 + (q < lim ? q : lim - 1);
                    u32 p = (u32)__shfl((int)pk_l, h * 32 + idx);
                    v[q] = x2[(size_t)(p & 0x1FFFFu) * 32 + l32];
                }
#pragma unroll
                for (int q = 0; q < 8; ++q) {                // static index only
                    if (q < lim) {
                        const u32 p = (u32)__shfl((int)pk_l, h * 32 + j0 + q);
                        const int b = (int)(p >> 17);
                        if (b != cur_bin) {                  // uniform within half
                            if (rcnt > 0) FLUSHH();
                            cur_bin = b; a0 = 0.f; a1 = 0.f; a2 = 0.f; a3 = 0.f; rcnt = 0;
                        }
                        const uint2 vv = v[q];
                        a0 += __uint_as_float(vv.x << 16);
                        a1 += __uint_as_float(vv.x & 0xffff0000u);
                        a2 += __uint_as_float(vv.y << 16);
                        a3 += __uint_as_float(vv.y & 0xffff0000u);
                        ++rcnt;
                    }
                }
            }
        }
        if (rcnt > 0) FLUSHH();
    }
    __syncthreads();

    // ---- phase 2: 9-chunk MFMA with B-prefetch. wave w owns cols [w*16,+16).
    const uint4* ATq = reinterpret_cast<const uint4*>(ACC);
    f32x4 accv[2];
    accv[0] = (f32x4)0.f; accv[1] = (f32x4)0.f;
    union { uint4 u; bf16x8 h_; } av, bv;
    const int colg = w * 16 + m;

    uint4 bcur[4], bnxt[4];
#pragma unroll
    for (int ks = 0; ks < 4; ++ks) bcur[ks] = Wt[(size_t)colg * 16 + ks * 4 + g];
#pragma unroll
    for (int ks = 0; ks < 4; ++ks) bnxt[ks] = Wt[2048 + (size_t)colg * 16 + ks * 4 + g];

    // chunk 0: root transform, A straight from global
#pragma unroll
    for (int ks = 0; ks < 4; ++ks) {
        bv.u = bcur[ks];
        bf16x8 bf = bv.h_;
#pragma unroll
        for (int mt = 0; mt < 2; ++mt) {
            av.u = x16[(size_t)(rowbase + mt * 16 + m) * 16 + ks * 4 + g];
            accv[mt] = __builtin_amdgcn_mfma_f32_16x16x32_bf16(av.h_, bf, accv[mt], 0, 0, 0);
        }
    }

    // chunks 1..8: A from swizzled LDS means; prefetch chunk r+2 B-frags
#pragma unroll
    for (int r = 0; r < 8; ++r) {
#pragma unroll
        for (int ks = 0; ks < 4; ++ks) bcur[ks] = bnxt[ks];
        if (r < 7) {
            const uint4* Wn = Wt + (size_t)(r + 2) * 2048;
#pragma unroll
            for (int ks = 0; ks < 4; ++ks) bnxt[ks] = Wn[(size_t)colg * 16 + ks * 4 + g];
        }
#pragma unroll
        for (int ks = 0; ks < 4; ++ks) {
            bv.u = bcur[ks];
            bf16x8 bf = bv.h_;
#pragma unroll
            for (int mt = 0; mt < 2; ++mt) {
                av.u = ATq[(size_t)((mt * 16 + m) * 8 + r) * 16 + (u32)((ks * 4 + g) ^ m)];
                accv[mt] = __builtin_amdgcn_mfma_f32_16x16x32_bf16(av.h_, bf, accv[mt], 0, 0, 0);
            }
        }
    }

    // epilogue: +bias, f32 store. C/D: col=m (B-col), row=g*4+j (A-row)
    {
        const float bb = bias[colg];
#pragma unroll
        for (int mt = 0; mt < 2; ++mt)
#pragma unroll
            for (int j = 0; j < 4; ++j)
                out[(size_t)(rowbase + mt * 16 + g * 4 + j) * DIM + colg] = accv[mt][j] + bb;
    }
}

// ---------------------------------------------------------------------------
extern "C" void kernel_launch(void* const* d_in, const int* in_sizes, int n_in,
                              void* d_out, int out_size, void* d_ws, size_t ws_size,
                              hipStream_t stream) {
    const float* x      = (const float*)d_in[0];
    const float* W      = (const float*)d_in[1];
    const float* W_root = (const float*)d_in[2];
    const float* bias   = (const float*)d_in[3];
    const int*   ei     = (const int*)d_in[4];   // [2][E]
    const int*   et     = (const int*)d_in[5];   // [E]
    float* out = (float*)d_out;

    char* ws = (char*)d_ws;
    uint4*          x_bf   = (uint4*)(ws);                        // 25,600,000
    unsigned short* Wt     = (unsigned short*)(ws + 25600000);    //    294,912
    u32*            starts = (u32*)(ws + 25894912);               //  3,200,016
    u32*            hist   = (u32*)(ws + 29094928);               //  3,200,000
    u32*            bsum   = (u32*)(ws + 32294928);               //      4,096
    u32*            rank   = (u32*)(ws + 32299024);               //  2,400,000
    u32*            spk    = (u32*)(ws + 34699024);               //  2,400,000
    // total 37,099,024 B

    hipMemsetAsync(hist, 0, (size_t)NBINS * 4, stream);
    prep<<<XBLOCKS + TBLOCKS + HBLOCKS, 256, 0, stream>>>(x, x_bf, W, W_root, Wt, ei, et, hist, rank);
    scan1<<<SCAN_NB, 256, 0, stream>>>(hist, bsum);
    scan2<<<1, 256, 0, stream>>>(bsum, SCAN_NB);
    scan3<<<SCAN_NB, 256, 0, stream>>>(hist, bsum, starts);
    reorder<<<HBLOCKS, 256, 0, stream>>>(ei, et, starts, rank, spk);
    rgcn_fused<<<N_NODES / 32, 512, 65536, stream>>>((const uint2*)x_bf, x_bf, (const uint4*)Wt,
                                                     starts, spk, bias, out);
}